// Round 8
// baseline (1761.396 us; speedup 1.0000x reference)
//
#include <hip/hip_runtime.h>
#include <hip/hip_bf16.h>
#include <stdint.h>

// FT-Transformer forward, MI355X gfx950. Round 8:
//  - gemm_big: 128x256 block tile, __launch_bounds__(256,1) (512-reg budget, no spill;
//    r6's failure was the (256,2) 256-reg cap + dynamic buffer indexing -> scratch).
//    Static-indexed reg double-buffer, 32 indep MFMA/iter hides latency at 1 wave/SIMD.
//  - attention v3: QK^T computed as S^T (K = A-operand) so softmax rows are lane-local
//    (2 shfls/pass); P -> PV B-frags via ds_write_b64 into frag-tiled LDS (stride-1
//    b128 reads, conflict-free). 45 KB LDS -> 3 blocks/CU. Vector 8B epilogue stores.

typedef __hip_bfloat16 bf16_t;
typedef __attribute__((ext_vector_type(8))) __bf16 bf16x8;
typedef __attribute__((ext_vector_type(4))) __bf16 bf16x4;
typedef __attribute__((ext_vector_type(4))) float floatx4;

constexpr int M_ROWS = 16512;          // 128 * 129
constexpr float SQRT_EMB_F = 22.627416997969522f;  // scores DIVIDED by emb**-0.5

__device__ __forceinline__ floatx4 mfma16(bf16x8 a, bf16x8 b, floatx4 c) {
  return __builtin_amdgcn_mfma_f32_16x16x32_bf16(a, b, c, 0, 0, 0);
}

// element offset of the 16B chunk holding (m, k..k+7) in fragment-tiled [M/16][KT][512]
__device__ __forceinline__ size_t frag_chunk(int m, int k, int KT) {
  return ((size_t)(m >> 4) * KT + (k >> 5)) * 512 + (m & 15) * 8 + 128 * ((k >> 3) & 3);
}
__device__ __forceinline__ size_t frag_elem(int m, int k, int KT) {
  return frag_chunk(m, k, KT) + (k & 7);
}

// ---------------- weight transform: W [L][K][N] fp32 -> frag-tiled bf16 [L][NP/16][KP/32][512]
// PERM=1: output col n maps to source col (n&1) ? 682+(n>>1) : (n>>1)  (ReGLU pairing)
template <int PERM>
__global__ __launch_bounds__(256) void transpose_cvt(const float* __restrict__ W,
    bf16_t* __restrict__ WT, int K, int N, int KP, int NP)
{
  __shared__ float tile[32][33];
  int k0 = blockIdx.x * 32, n0 = blockIdx.y * 32;
  const float* Wl = W + (size_t)blockIdx.z * K * N;
  bf16_t* WTl = WT + (size_t)blockIdx.z * NP * KP;
  const int KT = KP >> 5;
  #pragma unroll
  for (int r = 0; r < 32; r += 8) {
    int k = k0 + threadIdx.y + r, n = n0 + threadIdx.x;
    int srcn = PERM ? ((n & 1) ? 682 + (n >> 1) : (n >> 1)) : n;
    int valid = (k < K) && (PERM ? (n < 1364) : (n < N));
    tile[threadIdx.y + r][threadIdx.x] = valid ? Wl[(size_t)k * N + srcn] : 0.f;
  }
  __syncthreads();
  #pragma unroll
  for (int r = 0; r < 32; r += 8) {
    int n = n0 + threadIdx.y + r, k = k0 + threadIdx.x;
    if (n < NP && k < KP)
      WTl[frag_elem(n, k, KT)] = __float2bfloat16(tile[threadIdx.x][threadIdx.y + r]);
  }
}

// ---------------- feature tokenizer ----------------
__global__ __launch_bounds__(256) void tokenizer_kernel(const float* __restrict__ x,
    const float* __restrict__ tok_w, const float* __restrict__ tok_b,
    const float* __restrict__ cat_emb, float* __restrict__ h, bf16_t* __restrict__ ab)
{
  int row = blockIdx.x * 4 + (threadIdx.x >> 6);
  int lane = threadIdx.x & 63, e0 = lane * 8;
  int b = row / 129, t = row - b * 129;
  float v[8];
  if (t == 0) {
    #pragma unroll
    for (int u = 0; u < 8; u++) v[u] = tok_w[e0 + u];
  } else if (t <= 100) {
    float xv = x[(size_t)b * 128 + 28 + (t - 1)];
    const float* wp = tok_w + (size_t)t * 512 + e0;
    const float* bp = tok_b + (size_t)(t - 1) * 512 + e0;
    #pragma unroll
    for (int u = 0; u < 8; u++) v[u] = wp[u] * xv + bp[u];
  } else {
    int j = t - 101;
    int idx = (int)x[(size_t)b * 128 + j] + 100 * j;
    const float* cp = cat_emb + (size_t)idx * 512 + e0;
    const float* bp = tok_b + (size_t)(t - 1) * 512 + e0;
    #pragma unroll
    for (int u = 0; u < 8; u++) v[u] = cp[u] + bp[u];
  }
  float* hr = h + (size_t)row * 512 + e0;
  #pragma unroll
  for (int u = 0; u < 8; u++) hr[u] = v[u];
  bf16x8 o8;
  #pragma unroll
  for (int u = 0; u < 8; u++) o8[u] = (__bf16)__float2bfloat16(v[u]);
  *(bf16x8*)(ab + ((size_t)(row >> 4) * 16 + (lane >> 2)) * 512 + (row & 15) * 8 + 128 * (lane & 3)) = o8;
}

// ---------------- layernorm: one wave per row; out = frag-tiled bf16 (KT=16) ----------------
__global__ __launch_bounds__(256) void ln_kernel(const float* __restrict__ hin,
    bf16_t* __restrict__ out, const float* __restrict__ g, const float* __restrict__ bta)
{
  int row = blockIdx.x * 4 + (threadIdx.x >> 6);
  int lane = threadIdx.x & 63;
  const float* hr = hin + (size_t)row * 512 + lane * 8;
  float4 v0 = *(const float4*)hr;
  float4 v1 = *(const float4*)(hr + 4);
  float s = v0.x + v0.y + v0.z + v0.w + v1.x + v1.y + v1.z + v1.w;
  float q = v0.x * v0.x + v0.y * v0.y + v0.z * v0.z + v0.w * v0.w
          + v1.x * v1.x + v1.y * v1.y + v1.z * v1.z + v1.w * v1.w;
  #pragma unroll
  for (int o = 1; o < 64; o <<= 1) { s += __shfl_xor(s, o); q += __shfl_xor(q, o); }
  float mean = s * (1.f / 512.f);
  float var = q * (1.f / 512.f) - mean * mean;
  float rstd = rsqrtf(var + 1e-5f);
  float4 g0 = *(const float4*)(g + lane * 8);
  float4 g1 = *(const float4*)(g + lane * 8 + 4);
  float4 b0v = *(const float4*)(bta + lane * 8);
  float4 b1v = *(const float4*)(bta + lane * 8 + 4);
  bf16x8 o8;
  o8[0] = (__bf16)__float2bfloat16((v0.x - mean) * rstd * g0.x + b0v.x);
  o8[1] = (__bf16)__float2bfloat16((v0.y - mean) * rstd * g0.y + b0v.y);
  o8[2] = (__bf16)__float2bfloat16((v0.z - mean) * rstd * g0.z + b0v.z);
  o8[3] = (__bf16)__float2bfloat16((v0.w - mean) * rstd * g0.w + b0v.w);
  o8[4] = (__bf16)__float2bfloat16((v1.x - mean) * rstd * g1.x + b1v.x);
  o8[5] = (__bf16)__float2bfloat16((v1.y - mean) * rstd * g1.y + b1v.y);
  o8[6] = (__bf16)__float2bfloat16((v1.z - mean) * rstd * g1.z + b1v.z);
  o8[7] = (__bf16)__float2bfloat16((v1.w - mean) * rstd * g1.w + b1v.w);
  *(bf16x8*)(out + ((size_t)(row >> 4) * 16 + (lane >> 2)) * 512 + (row & 15) * 8 + 128 * (lane & 3)) = o8;
}

// ---------------- gemm_big 128x256: C = A * BT^T + bias; no LDS; 1 wave/SIMD ----------------
// A frag [M/16][K/32][512]; BT frag [N/16][K/32][512]. grid (N/256, M/128).
// Wave = 64x128: 4 m-tiles x 8 n-tiles, acc 128 regs (AGPR).
// MODE 0: out bf16 frag (KT=N/32). MODE 1: fp32 row-major = resid+acc+bias (N=512).
// MODE 2: ReGLU paired cols, out bf16 frag [M/16][(N/2)/32][512].
template <int MODE>
__global__ __launch_bounds__(256, 1) void gemm_big(const bf16_t* __restrict__ A,
    const bf16_t* __restrict__ BT, const float* __restrict__ bias, int biasN,
    const float* __restrict__ resid, void* __restrict__ outp, int K, int N)
{
  const int total = gridDim.x * gridDim.y;
  const int lin = blockIdx.y * gridDim.x + blockIdx.x;
  const int xcd = lin & 7, kb2 = lin >> 3;
  const int qch = total >> 3, rch = total & 7;
  const int idx = xcd * qch + (xcd < rch ? xcd : rch) + kb2;
  const int bm = idx / gridDim.x;
  const int bn = idx - bm * gridDim.x;
  const int m0 = bm * 128, n0 = bn * 256;

  const int tid = threadIdx.x;
  const int w = tid >> 6, l = tid & 63, l15 = l & 15, quad = l >> 4;
  const int wm = (w >> 1) * 64, wn = (w & 1) * 128;
  const int KT = K >> 5;

  const bf16_t* pa[4];
  const bf16_t* pb[8];
  #pragma unroll
  for (int i = 0; i < 4; i++)
    pa[i] = A + ((size_t)(((m0 + wm) >> 4) + i) * KT) * 512 + l * 8;
  #pragma unroll
  for (int j = 0; j < 8; j++)
    pb[j] = BT + ((size_t)(((n0 + wn) >> 4) + j) * KT) * 512 + l * 8;

  bf16x8 af[2][4], bg[2][8];
  #pragma unroll
  for (int i = 0; i < 4; i++) af[0][i] = *(const bf16x8*)pa[i];
  #pragma unroll
  for (int j = 0; j < 8; j++) bg[0][j] = *(const bf16x8*)pb[j];

  floatx4 z4 = {0.f, 0.f, 0.f, 0.f};
  floatx4 acc[4][8];
  #pragma unroll
  for (int i = 0; i < 4; i++)
    #pragma unroll
    for (int j = 0; j < 8; j++) acc[i][j] = z4;

  const int T = KT;  // 16 or 24 — even
  for (int t = 0; t < T; t += 2) {
    if (t + 1 < T) {
      #pragma unroll
      for (int i = 0; i < 4; i++) af[1][i] = *(const bf16x8*)(pa[i] + (size_t)(t + 1) * 512);
      #pragma unroll
      for (int j = 0; j < 8; j++) bg[1][j] = *(const bf16x8*)(pb[j] + (size_t)(t + 1) * 512);
    }
    #pragma unroll
    for (int i = 0; i < 4; i++)
      #pragma unroll
      for (int j = 0; j < 8; j++)
        acc[i][j] = mfma16(af[0][i], bg[0][j], acc[i][j]);
    if (t + 1 < T) {
      if (t + 2 < T) {
        #pragma unroll
        for (int i = 0; i < 4; i++) af[0][i] = *(const bf16x8*)(pa[i] + (size_t)(t + 2) * 512);
        #pragma unroll
        for (int j = 0; j < 8; j++) bg[0][j] = *(const bf16x8*)(pb[j] + (size_t)(t + 2) * 512);
      }
      #pragma unroll
      for (int i = 0; i < 4; i++)
        #pragma unroll
        for (int j = 0; j < 8; j++)
          acc[i][j] = mfma16(af[1][i], bg[1][j], acc[i][j]);
    }
  }

  #pragma unroll
  for (int j = 0; j < 8; j++) {
    int col = n0 + wn + j * 16 + l15;
    float bv = 0.f;
    if (MODE == 2) {
      if (col < biasN) bv = bias[(col & 1) ? 682 + (col >> 1) : (col >> 1)];
    } else {
      if (col < biasN) bv = bias[col];
    }
    #pragma unroll
    for (int i = 0; i < 4; i++) {
      int row_b = m0 + wm + i * 16 + quad * 4;
      #pragma unroll
      for (int r = 0; r < 4; r++) {
        float v = acc[i][j][r] + bv;
        int m = row_b + r;
        if (MODE == 2) {
          float other = __shfl_xor(v, 1);
          if (!(l15 & 1)) {
            int c2 = col >> 1;
            ((bf16_t*)outp)[frag_elem(m, c2, (N >> 1) >> 5)] =
                __float2bfloat16(v * fmaxf(other, 0.f));
          }
        } else if (MODE == 1) {
          size_t idx2 = (size_t)m * N + col;
          ((float*)outp)[idx2] = v + resid[idx2];
        } else {
          ((bf16_t*)outp)[frag_elem(m, col, N >> 5)] = __float2bfloat16(v);
        }
      }
    }
  }
}

// ---------------- fused attention v3: S^T layout, lane-local softmax ----------------
// Block = 320 threads (5 waves); grid 1024 = (b, hh). Wave w owns q-rows [w*32, w*32+32).
// V^T staged once into frag-tiled LDS (A-operand layout, stride-1 b128 reads).
// QK^T: K = A-operand -> S^T C-layout (lane l15 = q-row m, regs = s). Softmax per m:
// local 36-reduce + shfl_xor(16,32). P -> B-frag-layout LDS via ds_write_b64. PV per mt.
__global__ __launch_bounds__(320, 3) void attn_kernel(const bf16_t* __restrict__ qkv,
                                                      bf16_t* __restrict__ attnout)
{
  __shared__ __align__(16) __bf16 vt[4 * 5 * 512];     // 20 KB: tiles [dt][kc], frag-tiled
  __shared__ __align__(16) __bf16 pbuf[5][5 * 512];    // 25 KB: per-wave P tiles [kc]

  const int bh = blockIdx.x, b = bh >> 3, hh = bh & 7;
  const int tid = threadIdx.x;
  const int w = tid >> 6, l = tid & 63, l15 = l & 15, quad = l >> 4;
  const int rbase = b * 129;
  const int qt = w;
  __bf16* pw = pbuf[w];

  // zero V^T (covers s>=129), stage V^T into frag-tile layout
  for (int i = tid; i < 4 * 5 * 512 / 2; i += 320) ((unsigned int*)vt)[i] = 0u;
  __syncthreads();
  for (int c = tid; c < 129 * 8; c += 320) {
    int s = c >> 3, ch = c & 7;
    bf16x8 tv = *(const bf16x8*)(qkv + frag_chunk(rbase + s, hh * 192 + 128 + ch * 8, 48));
    int kc = s >> 5, s31 = s & 31;
    int base = ((ch >> 1) * 5 + kc) * 512 + 128 * (s31 >> 3) + (s31 & 7) + (ch & 1) * 64;
    #pragma unroll
    for (int j = 0; j < 8; j++) vt[base + j * 8] = tv[j];
  }
  __syncthreads();

  // Q fragments (B-operand: lane l15 = q-row)
  bf16x8 zq = {};
  bf16x8 aq[2][2];
  #pragma unroll
  for (int mt = 0; mt < 2; mt++) {
    int m = qt * 32 + mt * 16 + l15;
    #pragma unroll
    for (int t = 0; t < 2; t++)
      aq[mt][t] = (m < 129)
          ? *(const bf16x8*)(qkv + frag_chunk(rbase + m, hh * 192 + t * 32 + quad * 8, 48)) : zq;
  }

  // QK^T -> S^T: A = K (m'=s), B = Q (n'=m). sT[mt][st] rows = s = st*16+quad*4+r.
  floatx4 z4 = {0.f, 0.f, 0.f, 0.f};
  floatx4 sT[2][9];
  #pragma unroll
  for (int mt = 0; mt < 2; mt++)
    #pragma unroll
    for (int st = 0; st < 9; st++) sT[mt][st] = z4;
  #pragma unroll
  for (int st = 0; st < 9; st++) {
    int srow = st * 16 + l15;
    #pragma unroll
    for (int t = 0; t < 2; t++) {
      bf16x8 kf = (srow < 129)
          ? *(const bf16x8*)(qkv + frag_chunk(rbase + srow, hh * 192 + 64 + t * 32 + quad * 8, 48))
          : zq;
      sT[0][st] = mfma16(kf, aq[0][t], sT[0][st]);
      sT[1][st] = mfma16(kf, aq[1][t], sT[1][st]);
    }
  }

  // per-mt: softmax(softmax(S^T)) lane-local, write P B-frags to LDS, PV, store O
  const bool val8 = (quad == 0);   // st=8: only s=128 (quad==0, r==0) is valid
  #pragma unroll
  for (int mt = 0; mt < 2; mt++) {
    float v[9][4];
    #pragma unroll
    for (int st = 0; st < 9; st++)
      #pragma unroll
      for (int r = 0; r < 4; r++) v[st][r] = sT[mt][st][r] * SQRT_EMB_F;
    float mx = -3e38f;
    #pragma unroll
    for (int st = 0; st < 8; st++)
      #pragma unroll
      for (int r = 0; r < 4; r++) mx = fmaxf(mx, v[st][r]);
    if (val8) mx = fmaxf(mx, v[8][0]);
    mx = fmaxf(mx, __shfl_xor(mx, 16));
    mx = fmaxf(mx, __shfl_xor(mx, 32));
    float sum = 0.f;
    #pragma unroll
    for (int st = 0; st < 8; st++)
      #pragma unroll
      for (int r = 0; r < 4; r++) { v[st][r] = __expf(v[st][r] - mx); sum += v[st][r]; }
    v[8][0] = val8 ? __expf(v[8][0] - mx) : 0.f;
    v[8][1] = v[8][2] = v[8][3] = 0.f;
    sum += v[8][0];
    sum += __shfl_xor(sum, 16);
    sum += __shfl_xor(sum, 32);
    float inv = 1.f / sum;
    float mx2 = 0.f;
    #pragma unroll
    for (int st = 0; st < 8; st++)
      #pragma unroll
      for (int r = 0; r < 4; r++) { v[st][r] *= inv; mx2 = fmaxf(mx2, v[st][r]); }
    v[8][0] *= inv; mx2 = fmaxf(mx2, v[8][0]);
    mx2 = fmaxf(mx2, __shfl_xor(mx2, 16));
    mx2 = fmaxf(mx2, __shfl_xor(mx2, 32));
    float sum2 = 0.f;
    #pragma unroll
    for (int st = 0; st < 8; st++)
      #pragma unroll
      for (int r = 0; r < 4; r++) { v[st][r] = __expf(v[st][r] - mx2); sum2 += v[st][r]; }
    v[8][0] = val8 ? __expf(v[8][0] - mx2) : 0.f;
    sum2 += v[8][0];
    sum2 += __shfl_xor(sum2, 16);
    sum2 += __shfl_xor(sum2, 32);
    float inv2 = 1.f / sum2;

    // write P into B-frag-tiled LDS: tile kc = st>>1; element (m=l15, s_local)
    #pragma unroll
    for (int st = 0; st < 9; st++) {
      bf16x4 t4;
      #pragma unroll
      for (int r = 0; r < 4; r++) t4[r] = (__bf16)__float2bfloat16(v[st][r] * inv2);
      int off = (st >> 1) * 512 + l15 * 8 + 128 * ((st & 1) * 2 + (quad >> 1)) + (quad & 1) * 4;
      *(bf16x4*)&pw[off] = t4;
    }
    {
      bf16x4 t4;
      #pragma unroll
      for (int r = 0; r < 4; r++) t4[r] = (__bf16)__float2bfloat16(0.f);
      int off = 4 * 512 + l15 * 8 + 128 * (2 + (quad >> 1)) + (quad & 1) * 4;  // st=9 pad
      *(bf16x4*)&pw[off] = t4;
    }
    __builtin_amdgcn_s_waitcnt(0xC07F);  // lgkmcnt(0)
    asm volatile("" ::: "memory");

    // PV: A = V^T (m'=d), B = P (n'=m)
    floatx4 oacc[4];
    #pragma unroll
    for (int dt = 0; dt < 4; dt++) oacc[dt] = z4;
    #pragma unroll
    for (int kc = 0; kc < 5; kc++) {
      bf16x8 pf = *(const bf16x8*)&pw[kc * 512 + l * 8];
      #pragma unroll
      for (int dt = 0; dt < 4; dt++) {
        bf16x8 vf = *(const bf16x8*)&vt[(dt * 5 + kc) * 512 + l * 8];
        oacc[dt] = mfma16(vf, pf, oacc[dt]);
      }
    }
    int m = qt * 32 + mt * 16 + l15;
    if (m < 129) {
      #pragma unroll
      for (int dt = 0; dt < 4; dt++) {
        int c0 = hh * 64 + dt * 16 + quad * 4;
        bf16x4 t4;
        #pragma unroll
        for (int r = 0; r < 4; r++) t4[r] = (__bf16)__float2bfloat16(oacc[dt][r]);
        *(bf16x4*)(attnout + frag_elem(rbase + m, c0, 16)) = t4;
      }
    }
    asm volatile("" ::: "memory");  // pw reads complete (in-order DS) before next mt overwrites
  }
}

// ---------------- output: CLS rows ----------------
__global__ __launch_bounds__(256) void out_copy(const float* __restrict__ h,
                                                float* __restrict__ out)
{
  int b = blockIdx.x, e = threadIdx.x;
  out[(size_t)b * 512 + e]       = h[(size_t)b * 129 * 512 + e];
  out[(size_t)b * 512 + e + 256] = h[(size_t)b * 129 * 512 + e + 256];
}

// ---------------- host launcher ----------------
extern "C" void kernel_launch(void* const* d_in, const int* in_sizes, int n_in,
                              void* d_out, int out_size, void* d_ws, size_t ws_size,
                              hipStream_t stream)
{
  const float* x       = (const float*)d_in[0];
  const float* tok_w   = (const float*)d_in[1];
  const float* tok_b   = (const float*)d_in[2];
  const float* cat_emb = (const float*)d_in[3];
  const float* Wqkv    = (const float*)d_in[4];
  const float* bqkv    = (const float*)d_in[5];
  const float* Wout    = (const float*)d_in[6];
  const float* bout    = (const float*)d_in[7];
  const float* W0      = (const float*)d_in[8];
  const float* b0      = (const float*)d_in[9];
  const float* W1      = (const float*)d_in[10];
  const float* b1      = (const float*)d_in[11];
  const float* ln0_g   = (const float*)d_in[12];
  const float* ln0_b   = (const float*)d_in[13];
  const float* ln1_g   = (const float*)d_in[14];
  const float* ln1_b   = (const float*)d_in[15];

  size_t off = 0;
  char* base = (char*)d_ws;
  auto alloc = [&](size_t n) { char* p = base + off; off += (n + 255) & ~(size_t)255; return p; };
  float*  h     = (float*) alloc((size_t)M_ROWS * 512 * 4);
  bf16_t* ab    = (bf16_t*)alloc((size_t)M_ROWS * 512 * 2);   // LN out, frag KT=16
  bf16_t* qkv   = (bf16_t*)alloc((size_t)M_ROWS * 1536 * 2);  // frag KT=48
  bf16_t* attno = (bf16_t*)alloc((size_t)M_ROWS * 512 * 2);   // frag KT=16
  bf16_t* regl  = (bf16_t*)alloc((size_t)M_ROWS * 768 * 2);   // frag KT=24
  bf16_t* WqkvT = (bf16_t*)alloc((size_t)6 * 1536 * 512 * 2);
  bf16_t* WoutT = (bf16_t*)alloc((size_t)6 * 512 * 512 * 2);
  bf16_t* W0T   = (bf16_t*)alloc((size_t)6 * 1536 * 512 * 2);  // pair-interleaved, N-padded
  bf16_t* W1T   = (bf16_t*)alloc((size_t)6 * 512 * 768 * 2);   // K padded to 768
  (void)ws_size; (void)in_sizes; (void)n_in; (void)out_size;

  dim3 tb(32, 8, 1);
  transpose_cvt<0><<<dim3(16, 48, 6), tb, 0, stream>>>(Wqkv, WqkvT, 512, 1536, 512, 1536);
  transpose_cvt<0><<<dim3(16, 16, 6), tb, 0, stream>>>(Wout, WoutT, 512, 512, 512, 512);
  transpose_cvt<1><<<dim3(16, 48, 6), tb, 0, stream>>>(W0, W0T, 512, 1364, 512, 1536);
  transpose_cvt<0><<<dim3(24, 16, 6), tb, 0, stream>>>(W1, W1T, 682, 512, 768, 512);

  tokenizer_kernel<<<M_ROWS / 4, 256, 0, stream>>>(x, tok_w, tok_b, cat_emb, h, ab);

  for (int i = 0; i < 6; i++) {
    if (i)
      ln_kernel<<<M_ROWS / 4, 256, 0, stream>>>(h, ab, ln0_g + (size_t)i * 512,
                                                ln0_b + (size_t)i * 512);
    gemm_big<0><<<dim3(6, 129), 256, 0, stream>>>(
        ab, WqkvT + (size_t)i * 1536 * 512, bqkv + (size_t)i * 1536, 1536, nullptr, qkv, 512, 1536);
    attn_kernel<<<1024, 320, 0, stream>>>(qkv, attno);
    gemm_big<1><<<dim3(2, 129), 256, 0, stream>>>(
        attno, WoutT + (size_t)i * 512 * 512, bout + (size_t)i * 512, 512, h, h, 512, 512);
    ln_kernel<<<M_ROWS / 4, 256, 0, stream>>>(h, ab, ln1_g + (size_t)i * 512,
                                              ln1_b + (size_t)i * 512);
    gemm_big<2><<<dim3(6, 129), 256, 0, stream>>>(
        ab, W0T + (size_t)i * 1536 * 512, b0 + (size_t)i * 1364, 1364, nullptr, regl, 512, 1536);
    gemm_big<1><<<dim3(2, 129), 256, 0, stream>>>(
        regl, W1T + (size_t)i * 512 * 768, b1 + (size_t)i * 512, 512, h, h, 768, 512);
  }

  out_copy<<<128, 256, 0, stream>>>(h, (float*)d_out);
}

// Round 9
// 1475.772 us; speedup vs baseline: 1.1935x; 1.1935x over previous
//
#include <hip/hip_runtime.h>
#include <hip/hip_bf16.h>
#include <stdint.h>

// FT-Transformer forward, MI355X gfx950. Round 9:
//  - GEMM core reverted to round-5 128x128 LDS-free frag structure (r6/r8 big-tile
//    experiments: 1-2 waves/SIMD starves load delivery; occupancy x in-flight rules).
//  - K=512 GEMMs (QKV, W0): fully-unrolled KT=16 pipeline, A 2-buf + B 3-buf
//    (12 loads in flight/wave vs 8) at unchanged 3 waves/SIMD.
//  - attention v3 (S^T lane-local softmax) kept from round 8.

typedef __hip_bfloat16 bf16_t;
typedef __attribute__((ext_vector_type(8))) __bf16 bf16x8;
typedef __attribute__((ext_vector_type(4))) __bf16 bf16x4;
typedef __attribute__((ext_vector_type(4))) float floatx4;

constexpr int M_ROWS = 16512;          // 128 * 129
constexpr float SQRT_EMB_F = 22.627416997969522f;  // scores DIVIDED by emb**-0.5

__device__ __forceinline__ floatx4 mfma16(bf16x8 a, bf16x8 b, floatx4 c) {
  return __builtin_amdgcn_mfma_f32_16x16x32_bf16(a, b, c, 0, 0, 0);
}

__device__ __forceinline__ size_t frag_chunk(int m, int k, int KT) {
  return ((size_t)(m >> 4) * KT + (k >> 5)) * 512 + (m & 15) * 8 + 128 * ((k >> 3) & 3);
}
__device__ __forceinline__ size_t frag_elem(int m, int k, int KT) {
  return frag_chunk(m, k, KT) + (k & 7);
}

// ---------------- weight transform ----------------
template <int PERM>
__global__ __launch_bounds__(256) void transpose_cvt(const float* __restrict__ W,
    bf16_t* __restrict__ WT, int K, int N, int KP, int NP)
{
  __shared__ float tile[32][33];
  int k0 = blockIdx.x * 32, n0 = blockIdx.y * 32;
  const float* Wl = W + (size_t)blockIdx.z * K * N;
  bf16_t* WTl = WT + (size_t)blockIdx.z * NP * KP;
  const int KT = KP >> 5;
  #pragma unroll
  for (int r = 0; r < 32; r += 8) {
    int k = k0 + threadIdx.y + r, n = n0 + threadIdx.x;
    int srcn = PERM ? ((n & 1) ? 682 + (n >> 1) : (n >> 1)) : n;
    int valid = (k < K) && (PERM ? (n < 1364) : (n < N));
    tile[threadIdx.y + r][threadIdx.x] = valid ? Wl[(size_t)k * N + srcn] : 0.f;
  }
  __syncthreads();
  #pragma unroll
  for (int r = 0; r < 32; r += 8) {
    int n = n0 + threadIdx.y + r, k = k0 + threadIdx.x;
    if (n < NP && k < KP)
      WTl[frag_elem(n, k, KT)] = __float2bfloat16(tile[threadIdx.x][threadIdx.y + r]);
  }
}

// ---------------- feature tokenizer ----------------
__global__ __launch_bounds__(256) void tokenizer_kernel(const float* __restrict__ x,
    const float* __restrict__ tok_w, const float* __restrict__ tok_b,
    const float* __restrict__ cat_emb, float* __restrict__ h, bf16_t* __restrict__ ab)
{
  int row = blockIdx.x * 4 + (threadIdx.x >> 6);
  int lane = threadIdx.x & 63, e0 = lane * 8;
  int b = row / 129, t = row - b * 129;
  float v[8];
  if (t == 0) {
    #pragma unroll
    for (int u = 0; u < 8; u++) v[u] = tok_w[e0 + u];
  } else if (t <= 100) {
    float xv = x[(size_t)b * 128 + 28 + (t - 1)];
    const float* wp = tok_w + (size_t)t * 512 + e0;
    const float* bp = tok_b + (size_t)(t - 1) * 512 + e0;
    #pragma unroll
    for (int u = 0; u < 8; u++) v[u] = wp[u] * xv + bp[u];
  } else {
    int j = t - 101;
    int idx = (int)x[(size_t)b * 128 + j] + 100 * j;
    const float* cp = cat_emb + (size_t)idx * 512 + e0;
    const float* bp = tok_b + (size_t)(t - 1) * 512 + e0;
    #pragma unroll
    for (int u = 0; u < 8; u++) v[u] = cp[u] + bp[u];
  }
  float* hr = h + (size_t)row * 512 + e0;
  #pragma unroll
  for (int u = 0; u < 8; u++) hr[u] = v[u];
  bf16x8 o8;
  #pragma unroll
  for (int u = 0; u < 8; u++) o8[u] = (__bf16)__float2bfloat16(v[u]);
  *(bf16x8*)(ab + ((size_t)(row >> 4) * 16 + (lane >> 2)) * 512 + (row & 15) * 8 + 128 * (lane & 3)) = o8;
}

// ---------------- layernorm ----------------
__global__ __launch_bounds__(256) void ln_kernel(const float* __restrict__ hin,
    bf16_t* __restrict__ out, const float* __restrict__ g, const float* __restrict__ bta)
{
  int row = blockIdx.x * 4 + (threadIdx.x >> 6);
  int lane = threadIdx.x & 63;
  const float* hr = hin + (size_t)row * 512 + lane * 8;
  float4 v0 = *(const float4*)hr;
  float4 v1 = *(const float4*)(hr + 4);
  float s = v0.x + v0.y + v0.z + v0.w + v1.x + v1.y + v1.z + v1.w;
  float q = v0.x * v0.x + v0.y * v0.y + v0.z * v0.z + v0.w * v0.w
          + v1.x * v1.x + v1.y * v1.y + v1.z * v1.z + v1.w * v1.w;
  #pragma unroll
  for (int o = 1; o < 64; o <<= 1) { s += __shfl_xor(s, o); q += __shfl_xor(q, o); }
  float mean = s * (1.f / 512.f);
  float var = q * (1.f / 512.f) - mean * mean;
  float rstd = rsqrtf(var + 1e-5f);
  float4 g0 = *(const float4*)(g + lane * 8);
  float4 g1 = *(const float4*)(g + lane * 8 + 4);
  float4 b0v = *(const float4*)(bta + lane * 8);
  float4 b1v = *(const float4*)(bta + lane * 8 + 4);
  bf16x8 o8;
  o8[0] = (__bf16)__float2bfloat16((v0.x - mean) * rstd * g0.x + b0v.x);
  o8[1] = (__bf16)__float2bfloat16((v0.y - mean) * rstd * g0.y + b0v.y);
  o8[2] = (__bf16)__float2bfloat16((v0.z - mean) * rstd * g0.z + b0v.z);
  o8[3] = (__bf16)__float2bfloat16((v0.w - mean) * rstd * g0.w + b0v.w);
  o8[4] = (__bf16)__float2bfloat16((v1.x - mean) * rstd * g1.x + b1v.x);
  o8[5] = (__bf16)__float2bfloat16((v1.y - mean) * rstd * g1.y + b1v.y);
  o8[6] = (__bf16)__float2bfloat16((v1.z - mean) * rstd * g1.z + b1v.z);
  o8[7] = (__bf16)__float2bfloat16((v1.w - mean) * rstd * g1.w + b1v.w);
  *(bf16x8*)(out + ((size_t)(row >> 4) * 16 + (lane >> 2)) * 512 + (row & 15) * 8 + 128 * (lane & 3)) = o8;
}

// ---------------- shared epilogue for 128x128 frag GEMMs ----------------
template <int MODE>
__device__ __forceinline__ void gemm_epilogue(floatx4 (&acc)[4][4], int m0, int n0,
    int wm, int wn, int l15, int quad, const float* __restrict__ bias, int biasN,
    const float* __restrict__ resid, void* __restrict__ outp, int N)
{
  #pragma unroll
  for (int j = 0; j < 4; j++) {
    int col = n0 + wn + j * 16 + l15;
    float bv = 0.f;
    if (MODE == 2) {
      if (col < biasN) bv = bias[(col & 1) ? 682 + (col >> 1) : (col >> 1)];
    } else {
      if (col < biasN) bv = bias[col];
    }
    #pragma unroll
    for (int i = 0; i < 4; i++) {
      int row_b = m0 + wm + i * 16 + quad * 4;
      #pragma unroll
      for (int r = 0; r < 4; r++) {
        float v = acc[i][j][r] + bv;
        int m = row_b + r;
        if (MODE == 2) {
          float other = __shfl_xor(v, 1);
          if (!(l15 & 1)) {
            int c2 = col >> 1;
            ((bf16_t*)outp)[frag_elem(m, c2, (N >> 1) >> 5)] =
                __float2bfloat16(v * fmaxf(other, 0.f));
          }
        } else if (MODE == 1) {
          size_t idx2 = (size_t)m * N + col;
          ((float*)outp)[idx2] = v + resid[idx2];
        } else {
          ((bf16_t*)outp)[frag_elem(m, col, N >> 5)] = __float2bfloat16(v);
        }
      }
    }
  }
}

// ---------------- gemm_k512: K=512 (KT=16) fully unrolled, A 2-buf + B 3-buf ----------------
template <int MODE>
__global__ __launch_bounds__(256, 3) void gemm_k512(const bf16_t* __restrict__ A,
    const bf16_t* __restrict__ BT, const float* __restrict__ bias, int biasN,
    const float* __restrict__ resid, void* __restrict__ outp, int N)
{
  constexpr int KT = 16;
  const int total = gridDim.x * gridDim.y;
  const int lin = blockIdx.y * gridDim.x + blockIdx.x;
  const int xcd = lin & 7, kb2 = lin >> 3;
  const int qch = total >> 3, rch = total & 7;
  const int idx = xcd * qch + (xcd < rch ? xcd : rch) + kb2;
  const int bm = idx / gridDim.x;
  const int bn = idx - bm * gridDim.x;
  const int m0 = bm * 128, n0 = bn * 128;

  const int tid = threadIdx.x;
  const int w = tid >> 6, l = tid & 63, l15 = l & 15, quad = l >> 4;
  const int wm = (w >> 1) * 64, wn = (w & 1) * 64;

  const bf16_t* pa[4];
  const bf16_t* pb[4];
  #pragma unroll
  for (int i = 0; i < 4; i++) {
    pa[i] = A  + ((size_t)(((m0 + wm) >> 4) + i) * KT) * 512 + l * 8;
    pb[i] = BT + ((size_t)(((n0 + wn) >> 4) + i) * KT) * 512 + l * 8;
  }

  bf16x8 af[2][4], bg[3][4];
  #pragma unroll
  for (int i = 0; i < 4; i++) {
    af[0][i] = *(const bf16x8*)pa[i];
    bg[0][i] = *(const bf16x8*)pb[i];
    bg[1][i] = *(const bf16x8*)(pb[i] + 512);
  }

  floatx4 z4 = {0.f, 0.f, 0.f, 0.f};
  floatx4 acc[4][4];
  #pragma unroll
  for (int i = 0; i < 4; i++)
    #pragma unroll
    for (int j = 0; j < 4; j++) acc[i][j] = z4;

  #pragma unroll
  for (int t = 0; t < KT; t++) {
    const int ca = t & 1, cb = t % 3;
    if (t + 1 < KT) {
      #pragma unroll
      for (int i = 0; i < 4; i++)
        af[ca ^ 1][i] = *(const bf16x8*)(pa[i] + (size_t)(t + 1) * 512);
    }
    if (t + 2 < KT) {
      const int nb = (t + 2) % 3;
      #pragma unroll
      for (int i = 0; i < 4; i++)
        bg[nb][i] = *(const bf16x8*)(pb[i] + (size_t)(t + 2) * 512);
    }
    #pragma unroll
    for (int i = 0; i < 4; i++)
      #pragma unroll
      for (int j = 0; j < 4; j++)
        acc[i][j] = mfma16(af[ca][i], bg[cb][j], acc[i][j]);
  }

  gemm_epilogue<MODE>(acc, m0, n0, wm, wn, l15, quad, bias, biasN, resid, outp, N);
}

// ---------------- gemm_frag (round-5, runtime K): used for MODE-1 gemms ----------------
template <int MODE>
__global__ __launch_bounds__(256, 3) void gemm_frag(const bf16_t* __restrict__ A,
    const bf16_t* __restrict__ BT, const float* __restrict__ bias, int biasN,
    const float* __restrict__ resid, void* __restrict__ outp, int K, int N)
{
  const int total = gridDim.x * gridDim.y;
  const int lin = blockIdx.y * gridDim.x + blockIdx.x;
  const int xcd = lin & 7, kb2 = lin >> 3;
  const int qch = total >> 3, rch = total & 7;
  const int idx = xcd * qch + (xcd < rch ? xcd : rch) + kb2;
  const int bm = idx / gridDim.x;
  const int bn = idx - bm * gridDim.x;
  const int m0 = bm * 128, n0 = bn * 128;

  const int tid = threadIdx.x;
  const int w = tid >> 6, l = tid & 63, l15 = l & 15, quad = l >> 4;
  const int wm = (w >> 1) * 64, wn = (w & 1) * 64;
  const int KT = K >> 5;

  const bf16_t* pa[4];
  const bf16_t* pb[4];
  #pragma unroll
  for (int i = 0; i < 4; i++) {
    pa[i] = A  + ((size_t)(((m0 + wm) >> 4) + i) * KT) * 512 + l * 8;
    pb[i] = BT + ((size_t)(((n0 + wn) >> 4) + i) * KT) * 512 + l * 8;
  }

  bf16x8 af[2][4], bg[2][4];
  #pragma unroll
  for (int i = 0; i < 4; i++) {
    af[0][i] = *(const bf16x8*)pa[i];
    bg[0][i] = *(const bf16x8*)pb[i];
  }

  floatx4 z4 = {0.f, 0.f, 0.f, 0.f};
  floatx4 acc[4][4];
  #pragma unroll
  for (int i = 0; i < 4; i++)
    #pragma unroll
    for (int j = 0; j < 4; j++) acc[i][j] = z4;

  const int T = KT;
  for (int t = 0; t < T; t += 2) {
    if (t + 1 < T) {
      #pragma unroll
      for (int i = 0; i < 4; i++) {
        af[1][i] = *(const bf16x8*)(pa[i] + (size_t)(t + 1) * 512);
        bg[1][i] = *(const bf16x8*)(pb[i] + (size_t)(t + 1) * 512);
      }
    }
    #pragma unroll
    for (int i = 0; i < 4; i++)
      #pragma unroll
      for (int j = 0; j < 4; j++)
        acc[i][j] = mfma16(af[0][i], bg[0][j], acc[i][j]);
    if (t + 1 < T) {
      if (t + 2 < T) {
        #pragma unroll
        for (int i = 0; i < 4; i++) {
          af[0][i] = *(const bf16x8*)(pa[i] + (size_t)(t + 2) * 512);
          bg[0][i] = *(const bf16x8*)(pb[i] + (size_t)(t + 2) * 512);
        }
      }
      #pragma unroll
      for (int i = 0; i < 4; i++)
        #pragma unroll
        for (int j = 0; j < 4; j++)
          acc[i][j] = mfma16(af[1][i], bg[1][j], acc[i][j]);
    }
  }

  gemm_epilogue<MODE>(acc, m0, n0, wm, wn, l15, quad, bias, biasN, resid, outp, N);
}

// ---------------- fused attention v3 (round 8): S^T layout, lane-local softmax ----------------
__global__ __launch_bounds__(320, 3) void attn_kernel(const bf16_t* __restrict__ qkv,
                                                      bf16_t* __restrict__ attnout)
{
  __shared__ __align__(16) __bf16 vt[4 * 5 * 512];
  __shared__ __align__(16) __bf16 pbuf[5][5 * 512];

  const int bh = blockIdx.x, b = bh >> 3, hh = bh & 7;
  const int tid = threadIdx.x;
  const int w = tid >> 6, l = tid & 63, l15 = l & 15, quad = l >> 4;
  const int rbase = b * 129;
  const int qt = w;
  __bf16* pw = pbuf[w];

  for (int i = tid; i < 4 * 5 * 512 / 2; i += 320) ((unsigned int*)vt)[i] = 0u;
  __syncthreads();
  for (int c = tid; c < 129 * 8; c += 320) {
    int s = c >> 3, ch = c & 7;
    bf16x8 tv = *(const bf16x8*)(qkv + frag_chunk(rbase + s, hh * 192 + 128 + ch * 8, 48));
    int kc = s >> 5, s31 = s & 31;
    int base = ((ch >> 1) * 5 + kc) * 512 + 128 * (s31 >> 3) + (s31 & 7) + (ch & 1) * 64;
    #pragma unroll
    for (int j = 0; j < 8; j++) vt[base + j * 8] = tv[j];
  }
  __syncthreads();

  bf16x8 zq = {};
  bf16x8 aq[2][2];
  #pragma unroll
  for (int mt = 0; mt < 2; mt++) {
    int m = qt * 32 + mt * 16 + l15;
    #pragma unroll
    for (int t = 0; t < 2; t++)
      aq[mt][t] = (m < 129)
          ? *(const bf16x8*)(qkv + frag_chunk(rbase + m, hh * 192 + t * 32 + quad * 8, 48)) : zq;
  }

  floatx4 z4 = {0.f, 0.f, 0.f, 0.f};
  floatx4 sT[2][9];
  #pragma unroll
  for (int mt = 0; mt < 2; mt++)
    #pragma unroll
    for (int st = 0; st < 9; st++) sT[mt][st] = z4;
  #pragma unroll
  for (int st = 0; st < 9; st++) {
    int srow = st * 16 + l15;
    #pragma unroll
    for (int t = 0; t < 2; t++) {
      bf16x8 kf = (srow < 129)
          ? *(const bf16x8*)(qkv + frag_chunk(rbase + srow, hh * 192 + 64 + t * 32 + quad * 8, 48))
          : zq;
      sT[0][st] = mfma16(kf, aq[0][t], sT[0][st]);
      sT[1][st] = mfma16(kf, aq[1][t], sT[1][st]);
    }
  }

  const bool val8 = (quad == 0);
  #pragma unroll
  for (int mt = 0; mt < 2; mt++) {
    float v[9][4];
    #pragma unroll
    for (int st = 0; st < 9; st++)
      #pragma unroll
      for (int r = 0; r < 4; r++) v[st][r] = sT[mt][st][r] * SQRT_EMB_F;
    float mx = -3e38f;
    #pragma unroll
    for (int st = 0; st < 8; st++)
      #pragma unroll
      for (int r = 0; r < 4; r++) mx = fmaxf(mx, v[st][r]);
    if (val8) mx = fmaxf(mx, v[8][0]);
    mx = fmaxf(mx, __shfl_xor(mx, 16));
    mx = fmaxf(mx, __shfl_xor(mx, 32));
    float sum = 0.f;
    #pragma unroll
    for (int st = 0; st < 8; st++)
      #pragma unroll
      for (int r = 0; r < 4; r++) { v[st][r] = __expf(v[st][r] - mx); sum += v[st][r]; }
    v[8][0] = val8 ? __expf(v[8][0] - mx) : 0.f;
    v[8][1] = v[8][2] = v[8][3] = 0.f;
    sum += v[8][0];
    sum += __shfl_xor(sum, 16);
    sum += __shfl_xor(sum, 32);
    float inv = 1.f / sum;
    float mx2 = 0.f;
    #pragma unroll
    for (int st = 0; st < 8; st++)
      #pragma unroll
      for (int r = 0; r < 4; r++) { v[st][r] *= inv; mx2 = fmaxf(mx2, v[st][r]); }
    v[8][0] *= inv; mx2 = fmaxf(mx2, v[8][0]);
    mx2 = fmaxf(mx2, __shfl_xor(mx2, 16));
    mx2 = fmaxf(mx2, __shfl_xor(mx2, 32));
    float sum2 = 0.f;
    #pragma unroll
    for (int st = 0; st < 8; st++)
      #pragma unroll
      for (int r = 0; r < 4; r++) { v[st][r] = __expf(v[st][r] - mx2); sum2 += v[st][r]; }
    v[8][0] = val8 ? __expf(v[8][0] - mx2) : 0.f;
    sum2 += v[8][0];
    sum2 += __shfl_xor(sum2, 16);
    sum2 += __shfl_xor(sum2, 32);
    float inv2 = 1.f / sum2;

    #pragma unroll
    for (int st = 0; st < 9; st++) {
      bf16x4 t4;
      #pragma unroll
      for (int r = 0; r < 4; r++) t4[r] = (__bf16)__float2bfloat16(v[st][r] * inv2);
      int off = (st >> 1) * 512 + l15 * 8 + 128 * ((st & 1) * 2 + (quad >> 1)) + (quad & 1) * 4;
      *(bf16x4*)&pw[off] = t4;
    }
    {
      bf16x4 t4;
      #pragma unroll
      for (int r = 0; r < 4; r++) t4[r] = (__bf16)__float2bfloat16(0.f);
      int off = 4 * 512 + l15 * 8 + 128 * (2 + (quad >> 1)) + (quad & 1) * 4;
      *(bf16x4*)&pw[off] = t4;
    }
    __builtin_amdgcn_s_waitcnt(0xC07F);  // lgkmcnt(0)
    asm volatile("" ::: "memory");

    floatx4 oacc[4];
    #pragma unroll
    for (int dt = 0; dt < 4; dt++) oacc[dt] = z4;
    #pragma unroll
    for (int kc = 0; kc < 5; kc++) {
      bf16x8 pf = *(const bf16x8*)&pw[kc * 512 + l * 8];
      #pragma unroll
      for (int dt = 0; dt < 4; dt++) {
        bf16x8 vf = *(const bf16x8*)&vt[(dt * 5 + kc) * 512 + l * 8];
        oacc[dt] = mfma16(vf, pf, oacc[dt]);
      }
    }
    int m = qt * 32 + mt * 16 + l15;
    if (m < 129) {
      #pragma unroll
      for (int dt = 0; dt < 4; dt++) {
        int c0 = hh * 64 + dt * 16 + quad * 4;
        bf16x4 t4;
        #pragma unroll
        for (int r = 0; r < 4; r++) t4[r] = (__bf16)__float2bfloat16(oacc[dt][r]);
        *(bf16x4*)(attnout + frag_elem(rbase + m, c0, 16)) = t4;
      }
    }
    asm volatile("" ::: "memory");
  }
}

// ---------------- output: CLS rows ----------------
__global__ __launch_bounds__(256) void out_copy(const float* __restrict__ h,
                                                float* __restrict__ out)
{
  int b = blockIdx.x, e = threadIdx.x;
  out[(size_t)b * 512 + e]       = h[(size_t)b * 129 * 512 + e];
  out[(size_t)b * 512 + e + 256] = h[(size_t)b * 129 * 512 + e + 256];
}

// ---------------- host launcher ----------------
extern "C" void kernel_launch(void* const* d_in, const int* in_sizes, int n_in,
                              void* d_out, int out_size, void* d_ws, size_t ws_size,
                              hipStream_t stream)
{
  const float* x       = (const float*)d_in[0];
  const float* tok_w   = (const float*)d_in[1];
  const float* tok_b   = (const float*)d_in[2];
  const float* cat_emb = (const float*)d_in[3];
  const float* Wqkv    = (const float*)d_in[4];
  const float* bqkv    = (const float*)d_in[5];
  const float* Wout    = (const float*)d_in[6];
  const float* bout    = (const float*)d_in[7];
  const float* W0      = (const float*)d_in[8];
  const float* b0      = (const float*)d_in[9];
  const float* W1      = (const float*)d_in[10];
  const float* b1      = (const float*)d_in[11];
  const float* ln0_g   = (const float*)d_in[12];
  const float* ln0_b   = (const float*)d_in[13];
  const float* ln1_g   = (const float*)d_in[14];
  const float* ln1_b   = (const float*)d_in[15];

  size_t off = 0;
  char* base = (char*)d_ws;
  auto alloc = [&](size_t n) { char* p = base + off; off += (n + 255) & ~(size_t)255; return p; };
  float*  h     = (float*) alloc((size_t)M_ROWS * 512 * 4);
  bf16_t* ab    = (bf16_t*)alloc((size_t)M_ROWS * 512 * 2);   // LN out, frag KT=16
  bf16_t* qkv   = (bf16_t*)alloc((size_t)M_ROWS * 1536 * 2);  // frag KT=48
  bf16_t* attno = (bf16_t*)alloc((size_t)M_ROWS * 512 * 2);   // frag KT=16
  bf16_t* regl  = (bf16_t*)alloc((size_t)M_ROWS * 704 * 2);   // frag KT=22
  bf16_t* WqkvT = (bf16_t*)alloc((size_t)6 * 1536 * 512 * 2);
  bf16_t* WoutT = (bf16_t*)alloc((size_t)6 * 512 * 512 * 2);
  bf16_t* W0T   = (bf16_t*)alloc((size_t)6 * 1408 * 512 * 2);  // pair-interleaved
  bf16_t* W1T   = (bf16_t*)alloc((size_t)6 * 512 * 704 * 2);
  (void)ws_size; (void)in_sizes; (void)n_in; (void)out_size;

  dim3 tb(32, 8, 1);
  transpose_cvt<0><<<dim3(16, 48, 6), tb, 0, stream>>>(Wqkv, WqkvT, 512, 1536, 512, 1536);
  transpose_cvt<0><<<dim3(16, 16, 6), tb, 0, stream>>>(Wout, WoutT, 512, 512, 512, 512);
  transpose_cvt<1><<<dim3(16, 44, 6), tb, 0, stream>>>(W0, W0T, 512, 1364, 512, 1408);
  transpose_cvt<0><<<dim3(22, 16, 6), tb, 0, stream>>>(W1, W1T, 682, 512, 704, 512);

  tokenizer_kernel<<<M_ROWS / 4, 256, 0, stream>>>(x, tok_w, tok_b, cat_emb, h, ab);

  for (int i = 0; i < 6; i++) {
    if (i)
      ln_kernel<<<M_ROWS / 4, 256, 0, stream>>>(h, ab, ln0_g + (size_t)i * 512,
                                                ln0_b + (size_t)i * 512);
    gemm_k512<0><<<dim3(12, 129), 256, 0, stream>>>(
        ab, WqkvT + (size_t)i * 1536 * 512, bqkv + (size_t)i * 1536, 1536, nullptr, qkv, 1536);
    attn_kernel<<<1024, 320, 0, stream>>>(qkv, attno);
    gemm_frag<1><<<dim3(4, 129), 256, 0, stream>>>(
        attno, WoutT + (size_t)i * 512 * 512, bout + (size_t)i * 512, 512, h, h, 512, 512);
    ln_kernel<<<M_ROWS / 4, 256, 0, stream>>>(h, ab, ln1_g + (size_t)i * 512,
                                              ln1_b + (size_t)i * 512);
    gemm_k512<2><<<dim3(11, 129), 256, 0, stream>>>(
        ab, W0T + (size_t)i * 1408 * 512, b0 + (size_t)i * 1364, 1364, nullptr, regl, 1408);
    gemm_frag<1><<<dim3(4, 129), 256, 0, stream>>>(
        regl, W1T + (size_t)i * 512 * 704, b1 + (size_t)i * 512, 512, h, h, 704, 512);
  }

  out_copy<<<128, 256, 0, stream>>>(h, (float*)d_out);
}

// Round 10
// 1361.207 us; speedup vs baseline: 1.2940x; 1.0842x over previous
//
#include <hip/hip_runtime.h>
#include <hip/hip_bf16.h>
#include <stdint.h>

// FT-Transformer forward, MI355X gfx950. Round 10:
//  - GEMM: r5 loop structure (t+=2 reg double-buffer, LDS-free, runtime-K loop kept so
//    the compiler preserves the pipeline — r9 full unroll collapsed it), but wave tile
//    shrunk to 32x64 (acc 2x4 = 32 AGPR, ~102 regs/wave) with 64x128 block tiles and
//    __launch_bounds__(256,4): 4 waves/SIMD = 16 waves/CU (was 3/SIMD at 144 regs).
//    Model: per-wave k-step serializes (~300cyc latency vs 78cyc MFMA); MfmaUtil scales
//    with waves/CU. 2.3x TLP -> predict QKV 48 -> ~30 us.
//  - attention v3 (S^T lane-local softmax) + LN/tokenizer/frag layout unchanged.

typedef __hip_bfloat16 bf16_t;
typedef __attribute__((ext_vector_type(8))) __bf16 bf16x8;
typedef __attribute__((ext_vector_type(4))) __bf16 bf16x4;
typedef __attribute__((ext_vector_type(4))) float floatx4;

constexpr int M_ROWS = 16512;          // 128 * 129 = 258 * 64
constexpr float SQRT_EMB_F = 22.627416997969522f;  // scores DIVIDED by emb**-0.5

__device__ __forceinline__ floatx4 mfma16(bf16x8 a, bf16x8 b, floatx4 c) {
  return __builtin_amdgcn_mfma_f32_16x16x32_bf16(a, b, c, 0, 0, 0);
}

__device__ __forceinline__ size_t frag_chunk(int m, int k, int KT) {
  return ((size_t)(m >> 4) * KT + (k >> 5)) * 512 + (m & 15) * 8 + 128 * ((k >> 3) & 3);
}
__device__ __forceinline__ size_t frag_elem(int m, int k, int KT) {
  return frag_chunk(m, k, KT) + (k & 7);
}

// ---------------- weight transform ----------------
template <int PERM>
__global__ __launch_bounds__(256) void transpose_cvt(const float* __restrict__ W,
    bf16_t* __restrict__ WT, int K, int N, int KP, int NP)
{
  __shared__ float tile[32][33];
  int k0 = blockIdx.x * 32, n0 = blockIdx.y * 32;
  const float* Wl = W + (size_t)blockIdx.z * K * N;
  bf16_t* WTl = WT + (size_t)blockIdx.z * NP * KP;
  const int KT = KP >> 5;
  #pragma unroll
  for (int r = 0; r < 32; r += 8) {
    int k = k0 + threadIdx.y + r, n = n0 + threadIdx.x;
    int srcn = PERM ? ((n & 1) ? 682 + (n >> 1) : (n >> 1)) : n;
    int valid = (k < K) && (PERM ? (n < 1364) : (n < N));
    tile[threadIdx.y + r][threadIdx.x] = valid ? Wl[(size_t)k * N + srcn] : 0.f;
  }
  __syncthreads();
  #pragma unroll
  for (int r = 0; r < 32; r += 8) {
    int n = n0 + threadIdx.y + r, k = k0 + threadIdx.x;
    if (n < NP && k < KP)
      WTl[frag_elem(n, k, KT)] = __float2bfloat16(tile[threadIdx.x][threadIdx.y + r]);
  }
}

// ---------------- feature tokenizer ----------------
__global__ __launch_bounds__(256) void tokenizer_kernel(const float* __restrict__ x,
    const float* __restrict__ tok_w, const float* __restrict__ tok_b,
    const float* __restrict__ cat_emb, float* __restrict__ h, bf16_t* __restrict__ ab)
{
  int row = blockIdx.x * 4 + (threadIdx.x >> 6);
  int lane = threadIdx.x & 63, e0 = lane * 8;
  int b = row / 129, t = row - b * 129;
  float v[8];
  if (t == 0) {
    #pragma unroll
    for (int u = 0; u < 8; u++) v[u] = tok_w[e0 + u];
  } else if (t <= 100) {
    float xv = x[(size_t)b * 128 + 28 + (t - 1)];
    const float* wp = tok_w + (size_t)t * 512 + e0;
    const float* bp = tok_b + (size_t)(t - 1) * 512 + e0;
    #pragma unroll
    for (int u = 0; u < 8; u++) v[u] = wp[u] * xv + bp[u];
  } else {
    int j = t - 101;
    int idx = (int)x[(size_t)b * 128 + j] + 100 * j;
    const float* cp = cat_emb + (size_t)idx * 512 + e0;
    const float* bp = tok_b + (size_t)(t - 1) * 512 + e0;
    #pragma unroll
    for (int u = 0; u < 8; u++) v[u] = cp[u] + bp[u];
  }
  float* hr = h + (size_t)row * 512 + e0;
  #pragma unroll
  for (int u = 0; u < 8; u++) hr[u] = v[u];
  bf16x8 o8;
  #pragma unroll
  for (int u = 0; u < 8; u++) o8[u] = (__bf16)__float2bfloat16(v[u]);
  *(bf16x8*)(ab + ((size_t)(row >> 4) * 16 + (lane >> 2)) * 512 + (row & 15) * 8 + 128 * (lane & 3)) = o8;
}

// ---------------- layernorm ----------------
__global__ __launch_bounds__(256) void ln_kernel(const float* __restrict__ hin,
    bf16_t* __restrict__ out, const float* __restrict__ g, const float* __restrict__ bta)
{
  int row = blockIdx.x * 4 + (threadIdx.x >> 6);
  int lane = threadIdx.x & 63;
  const float* hr = hin + (size_t)row * 512 + lane * 8;
  float4 v0 = *(const float4*)hr;
  float4 v1 = *(const float4*)(hr + 4);
  float s = v0.x + v0.y + v0.z + v0.w + v1.x + v1.y + v1.z + v1.w;
  float q = v0.x * v0.x + v0.y * v0.y + v0.z * v0.z + v0.w * v0.w
          + v1.x * v1.x + v1.y * v1.y + v1.z * v1.z + v1.w * v1.w;
  #pragma unroll
  for (int o = 1; o < 64; o <<= 1) { s += __shfl_xor(s, o); q += __shfl_xor(q, o); }
  float mean = s * (1.f / 512.f);
  float var = q * (1.f / 512.f) - mean * mean;
  float rstd = rsqrtf(var + 1e-5f);
  float4 g0 = *(const float4*)(g + lane * 8);
  float4 g1 = *(const float4*)(g + lane * 8 + 4);
  float4 b0v = *(const float4*)(bta + lane * 8);
  float4 b1v = *(const float4*)(bta + lane * 8 + 4);
  bf16x8 o8;
  o8[0] = (__bf16)__float2bfloat16((v0.x - mean) * rstd * g0.x + b0v.x);
  o8[1] = (__bf16)__float2bfloat16((v0.y - mean) * rstd * g0.y + b0v.y);
  o8[2] = (__bf16)__float2bfloat16((v0.z - mean) * rstd * g0.z + b0v.z);
  o8[3] = (__bf16)__float2bfloat16((v0.w - mean) * rstd * g0.w + b0v.w);
  o8[4] = (__bf16)__float2bfloat16((v1.x - mean) * rstd * g1.x + b1v.x);
  o8[5] = (__bf16)__float2bfloat16((v1.y - mean) * rstd * g1.y + b1v.y);
  o8[6] = (__bf16)__float2bfloat16((v1.z - mean) * rstd * g1.z + b1v.z);
  o8[7] = (__bf16)__float2bfloat16((v1.w - mean) * rstd * g1.w + b1v.w);
  *(bf16x8*)(out + ((size_t)(row >> 4) * 16 + (lane >> 2)) * 512 + (row & 15) * 8 + 128 * (lane & 3)) = o8;
}

// ---------------- gemm64: 64x128 block tile, wave = 32x64 (acc 2x4), 4 waves/SIMD ----------------
// A frag [M/16][K/32][512]; BT frag [N/16][K/32][512]. grid (N/128, M/64).
// MODE 0: out bf16 frag (KT=N/32). MODE 1: fp32 row-major = resid+acc+bias (N=512).
// MODE 2: ReGLU paired cols, out bf16 frag [M/16][(N/2)/32][512].
template <int MODE>
__global__ __launch_bounds__(256, 4) void gemm64(const bf16_t* __restrict__ A,
    const bf16_t* __restrict__ BT, const float* __restrict__ bias, int biasN,
    const float* __restrict__ resid, void* __restrict__ outp, int K, int N)
{
  // XCD-aware remap: consecutive remapped ids share the A m-block across n-blocks
  const int total = gridDim.x * gridDim.y;
  const int lin = blockIdx.y * gridDim.x + blockIdx.x;
  const int xcd = lin & 7, kb2 = lin >> 3;
  const int qch = total >> 3, rch = total & 7;
  const int idx = xcd * qch + (xcd < rch ? xcd : rch) + kb2;
  const int bm = idx / gridDim.x;
  const int bn = idx - bm * gridDim.x;
  const int m0 = bm * 64, n0 = bn * 128;

  const int tid = threadIdx.x;
  const int w = tid >> 6, l = tid & 63, l15 = l & 15, quad = l >> 4;
  const int wm = (w >> 1) * 32, wn = (w & 1) * 64;
  const int KT = K >> 5;

  const bf16_t* pa[2];
  const bf16_t* pb[4];
  #pragma unroll
  for (int i = 0; i < 2; i++)
    pa[i] = A  + ((size_t)(((m0 + wm) >> 4) + i) * KT) * 512 + l * 8;
  #pragma unroll
  for (int j = 0; j < 4; j++)
    pb[j] = BT + ((size_t)(((n0 + wn) >> 4) + j) * KT) * 512 + l * 8;

  bf16x8 af[2][2], bg[2][4];
  #pragma unroll
  for (int i = 0; i < 2; i++) af[0][i] = *(const bf16x8*)pa[i];
  #pragma unroll
  for (int j = 0; j < 4; j++) bg[0][j] = *(const bf16x8*)pb[j];

  floatx4 z4 = {0.f, 0.f, 0.f, 0.f};
  floatx4 acc[2][4];
  #pragma unroll
  for (int i = 0; i < 2; i++)
    #pragma unroll
    for (int j = 0; j < 4; j++) acc[i][j] = z4;

  const int T = KT;  // 16 or 22 — even
  for (int t = 0; t < T; t += 2) {
    if (t + 1 < T) {
      #pragma unroll
      for (int i = 0; i < 2; i++) af[1][i] = *(const bf16x8*)(pa[i] + (size_t)(t + 1) * 512);
      #pragma unroll
      for (int j = 0; j < 4; j++) bg[1][j] = *(const bf16x8*)(pb[j] + (size_t)(t + 1) * 512);
    }
    #pragma unroll
    for (int i = 0; i < 2; i++)
      #pragma unroll
      for (int j = 0; j < 4; j++)
        acc[i][j] = mfma16(af[0][i], bg[0][j], acc[i][j]);
    if (t + 1 < T) {
      if (t + 2 < T) {
        #pragma unroll
        for (int i = 0; i < 2; i++) af[0][i] = *(const bf16x8*)(pa[i] + (size_t)(t + 2) * 512);
        #pragma unroll
        for (int j = 0; j < 4; j++) bg[0][j] = *(const bf16x8*)(pb[j] + (size_t)(t + 2) * 512);
      }
      #pragma unroll
      for (int i = 0; i < 2; i++)
        #pragma unroll
        for (int j = 0; j < 4; j++)
          acc[i][j] = mfma16(af[1][i], bg[1][j], acc[i][j]);
    }
  }

  #pragma unroll
  for (int j = 0; j < 4; j++) {
    int col = n0 + wn + j * 16 + l15;
    float bv = 0.f;
    if (MODE == 2) {
      if (col < biasN) bv = bias[(col & 1) ? 682 + (col >> 1) : (col >> 1)];
    } else {
      if (col < biasN) bv = bias[col];
    }
    #pragma unroll
    for (int i = 0; i < 2; i++) {
      int row_b = m0 + wm + i * 16 + quad * 4;
      #pragma unroll
      for (int r = 0; r < 4; r++) {
        float v = acc[i][j][r] + bv;
        int m = row_b + r;
        if (MODE == 2) {
          float other = __shfl_xor(v, 1);
          if (!(l15 & 1)) {
            int c2 = col >> 1;
            ((bf16_t*)outp)[frag_elem(m, c2, (N >> 1) >> 5)] =
                __float2bfloat16(v * fmaxf(other, 0.f));
          }
        } else if (MODE == 1) {
          size_t idx2 = (size_t)m * N + col;
          ((float*)outp)[idx2] = v + resid[idx2];
        } else {
          ((bf16_t*)outp)[frag_elem(m, col, N >> 5)] = __float2bfloat16(v);
        }
      }
    }
  }
}

// ---------------- fused attention v3 (round 8): S^T layout, lane-local softmax ----------------
__global__ __launch_bounds__(320, 3) void attn_kernel(const bf16_t* __restrict__ qkv,
                                                      bf16_t* __restrict__ attnout)
{
  __shared__ __align__(16) __bf16 vt[4 * 5 * 512];
  __shared__ __align__(16) __bf16 pbuf[5][5 * 512];

  const int bh = blockIdx.x, b = bh >> 3, hh = bh & 7;
  const int tid = threadIdx.x;
  const int w = tid >> 6, l = tid & 63, l15 = l & 15, quad = l >> 4;
  const int rbase = b * 129;
  const int qt = w;
  __bf16* pw = pbuf[w];

  for (int i = tid; i < 4 * 5 * 512 / 2; i += 320) ((unsigned int*)vt)[i] = 0u;
  __syncthreads();
  for (int c = tid; c < 129 * 8; c += 320) {
    int s = c >> 3, ch = c & 7;
    bf16x8 tv = *(const bf16x8*)(qkv + frag_chunk(rbase + s, hh * 192 + 128 + ch * 8, 48));
    int kc = s >> 5, s31 = s & 31;
    int base = ((ch >> 1) * 5 + kc) * 512 + 128 * (s31 >> 3) + (s31 & 7) + (ch & 1) * 64;
    #pragma unroll
    for (int j = 0; j < 8; j++) vt[base + j * 8] = tv[j];
  }
  __syncthreads();

  bf16x8 zq = {};
  bf16x8 aq[2][2];
  #pragma unroll
  for (int mt = 0; mt < 2; mt++) {
    int m = qt * 32 + mt * 16 + l15;
    #pragma unroll
    for (int t = 0; t < 2; t++)
      aq[mt][t] = (m < 129)
          ? *(const bf16x8*)(qkv + frag_chunk(rbase + m, hh * 192 + t * 32 + quad * 8, 48)) : zq;
  }

  floatx4 z4 = {0.f, 0.f, 0.f, 0.f};
  floatx4 sT[2][9];
  #pragma unroll
  for (int mt = 0; mt < 2; mt++)
    #pragma unroll
    for (int st = 0; st < 9; st++) sT[mt][st] = z4;
  #pragma unroll
  for (int st = 0; st < 9; st++) {
    int srow = st * 16 + l15;
    #pragma unroll
    for (int t = 0; t < 2; t++) {
      bf16x8 kf = (srow < 129)
          ? *(const bf16x8*)(qkv + frag_chunk(rbase + srow, hh * 192 + 64 + t * 32 + quad * 8, 48))
          : zq;
      sT[0][st] = mfma16(kf, aq[0][t], sT[0][st]);
      sT[1][st] = mfma16(kf, aq[1][t], sT[1][st]);
    }
  }

  const bool val8 = (quad == 0);
  #pragma unroll
  for (int mt = 0; mt < 2; mt++) {
    float v[9][4];
    #pragma unroll
    for (int st = 0; st < 9; st++)
      #pragma unroll
      for (int r = 0; r < 4; r++) v[st][r] = sT[mt][st][r] * SQRT_EMB_F;
    float mx = -3e38f;
    #pragma unroll
    for (int st = 0; st < 8; st++)
      #pragma unroll
      for (int r = 0; r < 4; r++) mx = fmaxf(mx, v[st][r]);
    if (val8) mx = fmaxf(mx, v[8][0]);
    mx = fmaxf(mx, __shfl_xor(mx, 16));
    mx = fmaxf(mx, __shfl_xor(mx, 32));
    float sum = 0.f;
    #pragma unroll
    for (int st = 0; st < 8; st++)
      #pragma unroll
      for (int r = 0; r < 4; r++) { v[st][r] = __expf(v[st][r] - mx); sum += v[st][r]; }
    v[8][0] = val8 ? __expf(v[8][0] - mx) : 0.f;
    v[8][1] = v[8][2] = v[8][3] = 0.f;
    sum += v[8][0];
    sum += __shfl_xor(sum, 16);
    sum += __shfl_xor(sum, 32);
    float inv = 1.f / sum;
    float mx2 = 0.f;
    #pragma unroll
    for (int st = 0; st < 8; st++)
      #pragma unroll
      for (int r = 0; r < 4; r++) { v[st][r] *= inv; mx2 = fmaxf(mx2, v[st][r]); }
    v[8][0] *= inv; mx2 = fmaxf(mx2, v[8][0]);
    mx2 = fmaxf(mx2, __shfl_xor(mx2, 16));
    mx2 = fmaxf(mx2, __shfl_xor(mx2, 32));
    float sum2 = 0.f;
    #pragma unroll
    for (int st = 0; st < 8; st++)
      #pragma unroll
      for (int r = 0; r < 4; r++) { v[st][r] = __expf(v[st][r] - mx2); sum2 += v[st][r]; }
    v[8][0] = val8 ? __expf(v[8][0] - mx2) : 0.f;
    sum2 += v[8][0];
    sum2 += __shfl_xor(sum2, 16);
    sum2 += __shfl_xor(sum2, 32);
    float inv2 = 1.f / sum2;

    #pragma unroll
    for (int st = 0; st < 9; st++) {
      bf16x4 t4;
      #pragma unroll
      for (int r = 0; r < 4; r++) t4[r] = (__bf16)__float2bfloat16(v[st][r] * inv2);
      int off = (st >> 1) * 512 + l15 * 8 + 128 * ((st & 1) * 2 + (quad >> 1)) + (quad & 1) * 4;
      *(bf16x4*)&pw[off] = t4;
    }
    {
      bf16x4 t4;
      #pragma unroll
      for (int r = 0; r < 4; r++) t4[r] = (__bf16)__float2bfloat16(0.f);
      int off = 4 * 512 + l15 * 8 + 128 * (2 + (quad >> 1)) + (quad & 1) * 4;
      *(bf16x4*)&pw[off] = t4;
    }
    __builtin_amdgcn_s_waitcnt(0xC07F);  // lgkmcnt(0)
    asm volatile("" ::: "memory");

    floatx4 oacc[4];
    #pragma unroll
    for (int dt = 0; dt < 4; dt++) oacc[dt] = z4;
    #pragma unroll
    for (int kc = 0; kc < 5; kc++) {
      bf16x8 pf = *(const bf16x8*)&pw[kc * 512 + l * 8];
      #pragma unroll
      for (int dt = 0; dt < 4; dt++) {
        bf16x8 vf = *(const bf16x8*)&vt[(dt * 5 + kc) * 512 + l * 8];
        oacc[dt] = mfma16(vf, pf, oacc[dt]);
      }
    }
    int m = qt * 32 + mt * 16 + l15;
    if (m < 129) {
      #pragma unroll
      for (int dt = 0; dt < 4; dt++) {
        int c0 = hh * 64 + dt * 16 + quad * 4;
        bf16x4 t4;
        #pragma unroll
        for (int r = 0; r < 4; r++) t4[r] = (__bf16)__float2bfloat16(oacc[dt][r]);
        *(bf16x4*)(attnout + frag_elem(rbase + m, c0, 16)) = t4;
      }
    }
    asm volatile("" ::: "memory");
  }
}

// ---------------- output: CLS rows ----------------
__global__ __launch_bounds__(256) void out_copy(const float* __restrict__ h,
                                                float* __restrict__ out)
{
  int b = blockIdx.x, e = threadIdx.x;
  out[(size_t)b * 512 + e]       = h[(size_t)b * 129 * 512 + e];
  out[(size_t)b * 512 + e + 256] = h[(size_t)b * 129 * 512 + e + 256];
}

// ---------------- host launcher ----------------
extern "C" void kernel_launch(void* const* d_in, const int* in_sizes, int n_in,
                              void* d_out, int out_size, void* d_ws, size_t ws_size,
                              hipStream_t stream)
{
  const float* x       = (const float*)d_in[0];
  const float* tok_w   = (const float*)d_in[1];
  const float* tok_b   = (const float*)d_in[2];
  const float* cat_emb = (const float*)d_in[3];
  const float* Wqkv    = (const float*)d_in[4];
  const float* bqkv    = (const float*)d_in[5];
  const float* Wout    = (const float*)d_in[6];
  const float* bout    = (const float*)d_in[7];
  const float* W0      = (const float*)d_in[8];
  const float* b0      = (const float*)d_in[9];
  const float* W1      = (const float*)d_in[10];
  const float* b1      = (const float*)d_in[11];
  const float* ln0_g   = (const float*)d_in[12];
  const float* ln0_b   = (const float*)d_in[13];
  const float* ln1_g   = (const float*)d_in[14];
  const float* ln1_b   = (const float*)d_in[15];

  size_t off = 0;
  char* base = (char*)d_ws;
  auto alloc = [&](size_t n) { char* p = base + off; off += (n + 255) & ~(size_t)255; return p; };
  float*  h     = (float*) alloc((size_t)M_ROWS * 512 * 4);
  bf16_t* ab    = (bf16_t*)alloc((size_t)M_ROWS * 512 * 2);   // LN out, frag KT=16
  bf16_t* qkv   = (bf16_t*)alloc((size_t)M_ROWS * 1536 * 2);  // frag KT=48
  bf16_t* attno = (bf16_t*)alloc((size_t)M_ROWS * 512 * 2);   // frag KT=16
  bf16_t* regl  = (bf16_t*)alloc((size_t)M_ROWS * 704 * 2);   // frag KT=22
  bf16_t* WqkvT = (bf16_t*)alloc((size_t)6 * 1536 * 512 * 2);
  bf16_t* WoutT = (bf16_t*)alloc((size_t)6 * 512 * 512 * 2);
  bf16_t* W0T   = (bf16_t*)alloc((size_t)6 * 1408 * 512 * 2);  // pair-interleaved
  bf16_t* W1T   = (bf16_t*)alloc((size_t)6 * 512 * 704 * 2);
  (void)ws_size; (void)in_sizes; (void)n_in; (void)out_size;

  dim3 tb(32, 8, 1);
  transpose_cvt<0><<<dim3(16, 48, 6), tb, 0, stream>>>(Wqkv, WqkvT, 512, 1536, 512, 1536);
  transpose_cvt<0><<<dim3(16, 16, 6), tb, 0, stream>>>(Wout, WoutT, 512, 512, 512, 512);
  transpose_cvt<1><<<dim3(16, 44, 6), tb, 0, stream>>>(W0, W0T, 512, 1364, 512, 1408);
  transpose_cvt<0><<<dim3(22, 16, 6), tb, 0, stream>>>(W1, W1T, 682, 512, 704, 512);

  tokenizer_kernel<<<M_ROWS / 4, 256, 0, stream>>>(x, tok_w, tok_b, cat_emb, h, ab);

  for (int i = 0; i < 6; i++) {
    if (i)
      ln_kernel<<<M_ROWS / 4, 256, 0, stream>>>(h, ab, ln0_g + (size_t)i * 512,
                                                ln0_b + (size_t)i * 512);
    gemm64<0><<<dim3(12, 258), 256, 0, stream>>>(
        ab, WqkvT + (size_t)i * 1536 * 512, bqkv + (size_t)i * 1536, 1536, nullptr, qkv, 512, 1536);
    attn_kernel<<<1024, 320, 0, stream>>>(qkv, attno);
    gemm64<1><<<dim3(4, 258), 256, 0, stream>>>(
        attno, WoutT + (size_t)i * 512 * 512, bout + (size_t)i * 512, 512, h, h, 512, 512);
    ln_kernel<<<M_ROWS / 4, 256, 0, stream>>>(h, ab, ln1_g + (size_t)i * 512,
                                              ln1_b + (size_t)i * 512);
    gemm64<2><<<dim3(11, 258), 256, 0, stream>>>(
        ab, W0T + (size_t)i * 1408 * 512, b0 + (size_t)i * 1364, 1364, nullptr, regl, 512, 1408);
    gemm64<1><<<dim3(4, 258), 256, 0, stream>>>(
        regl, W1T + (size_t)i * 512 * 704, b1 + (size_t)i * 512, 512, h, h, 704, 512);
  }

  out_copy<<<128, 256, 0, stream>>>(h, (float*)d_out);
}